// Round 6
// baseline (237.274 us; speedup 1.0000x reference)
//
#include <hip/hip_runtime.h>

#define WIDTH  1024
#define HALF   512
#define DEPTH  32
#define BATCH  32768
#define PAIRS4 (HALF / 4)        // 128 float4 pairs per row
#define NTHREADS 256
#define NBLOCKS  2048            // NTHREADS*NBLOCKS = 524288 threads = total/8
#define ROWS_PER_THREAD 8
#define ROW_STRIDE 4096          // BATCH / ROWS_PER_THREAD

typedef float f4 __attribute__((ext_vector_type(4)));

// Static device-side gain table (2 KB). Avoids any dependency on d_ws.
__device__ float g_gains[HALF];

// ---------------------------------------------------------------------------
// Kernel 1: compute per-feature half-gains g[j] = 0.5 * prod_i (1 - 2*p[j,i]).
// Only 512 threads total -> the uncoalesced params reads happen ONCE, not in
// every one of 524288 streaming threads (the Round-2 bottleneck: ~1 GB of
// replicated L2 traffic).
// ---------------------------------------------------------------------------
__global__ void __launch_bounds__(256)
compute_gains(const float* __restrict__ params) {
    const int j = blockIdx.x * 256 + threadIdx.x;   // 0..511
    const f4* prow = (const f4*)(params + j * DEPTH);
    f4 prod = {1.0f, 1.0f, 1.0f, 1.0f};
#pragma unroll
    for (int c = 0; c < DEPTH / 4; ++c) {
        f4 p = prow[c];
        prod *= (1.0f - 2.0f * p);
    }
    g_gains[j] = 0.5f * (prod.x * prod.y * prod.z * prod.w);
}

// ---------------------------------------------------------------------------
// Kernel 2: pure stream. Depth scan collapses analytically: s=x0+x1 invariant,
// d=x0-x1 scales by g. out0 = 0.5*s + d*(0.5*g), out1 = 0.5*s - d*(0.5*g).
//
// NO nontemporal hints this round: `out` (128 MiB) fits in the 256 MiB
// Infinity Cache and is overwritten by the harness's next poison fill, so
// temporal stores let the IC absorb the write stream instead of punching
// ~134 MB through to HBM (Round-2 WRITE_SIZE showed 100% HBM write traffic
// under nt). Temporal loads likewise maximize X's IC hit rate (was ~50%).
// ---------------------------------------------------------------------------
__global__ void __launch_bounds__(NTHREADS)
butterfly_fused(const float* __restrict__ X,
                float* __restrict__ out) {
    const int tid0  = blockIdx.x * NTHREADS + threadIdx.x;
    const int jv    = tid0 & (PAIRS4 - 1);      // float4-pair index, constant
    const int brow0 = tid0 >> 7;                // first row, 0..4095

    const float* xbase = X   + (long long)brow0 * WIDTH + 4 * jv;
    float*       obase = out + (long long)brow0 * WIDTH + 4 * jv;

    // One coalesced, L2-resident 16B load: lanes read consecutive 16B chunks.
    const f4 g2 = ((const f4*)g_gains)[jv];

    // Explicit 2-deep software pipeline: next row's loads are in flight while
    // the current row computes/stores.
    f4 x0 = *((const f4*)(xbase));
    f4 x1 = *((const f4*)(xbase + HALF));

#pragma unroll
    for (int k = 0; k < ROWS_PER_THREAD; ++k) {
        f4 n0, n1;
        if (k + 1 < ROWS_PER_THREAD) {
            const long long noff = (long long)(k + 1) * ROW_STRIDE * WIDTH;
            n0 = *((const f4*)(xbase + noff));
            n1 = *((const f4*)(xbase + noff + HALF));
        }
        const long long off = (long long)k * ROW_STRIDE * WIDTH;
        f4 h = 0.5f * x0 + 0.5f * x1;       // 4 mul + 4 fma
        f4 e = (x0 - x1) * g2;              // 4 sub + 4 mul
        *((f4*)(obase + off))        = h + e;
        *((f4*)(obase + off + HALF)) = h - e;
        x0 = n0;
        x1 = n1;
    }
}

extern "C" void kernel_launch(void* const* d_in, const int* in_sizes, int n_in,
                              void* d_out, int out_size, void* d_ws, size_t ws_size,
                              hipStream_t stream) {
    const float* X      = (const float*)d_in[0];
    const float* params = (const float*)d_in[1];
    float* out = (float*)d_out;

    hipLaunchKernelGGL(compute_gains, dim3(2), dim3(256), 0, stream, params);
    hipLaunchKernelGGL(butterfly_fused, dim3(NBLOCKS), dim3(NTHREADS), 0, stream,
                       X, out);
}

// Round 8
// 226.177 us; speedup vs baseline: 1.0491x; 1.0491x over previous
//
#include <hip/hip_runtime.h>

#define WIDTH  1024
#define HALF   512
#define DEPTH  32
#define BATCH  32768
#define PAIRS4 (HALF / 4)        // 128 float4 pairs per row
#define NTHREADS 256
#define NBLOCKS  2048            // NTHREADS*NBLOCKS = 524288 threads = total/8
#define ROWS_PER_THREAD 8
#define ROW_STRIDE 4096          // BATCH / ROWS_PER_THREAD
#define BATCH_ROWS 4             // rows per load-batch (8 loads in flight)

typedef float f4 __attribute__((ext_vector_type(4)));

// Static device-side gain table (2 KB). No dependency on d_ws.
__device__ float g_gains[HALF];

// ---------------------------------------------------------------------------
// Kernel 1: per-feature half-gains g[j] = 0.5 * prod_i (1 - 2*p[j,i]).
// 512 threads total -> uncoalesced params reads happen ONCE (Round-2 lesson:
// doing this in every streaming thread cost ~1 GB of replicated L2 traffic).
// ---------------------------------------------------------------------------
__global__ void __launch_bounds__(256)
compute_gains(const float* __restrict__ params) {
    const int j = blockIdx.x * 256 + threadIdx.x;   // 0..511
    const f4* prow = (const f4*)(params + j * DEPTH);
    f4 prod = {1.0f, 1.0f, 1.0f, 1.0f};
#pragma unroll
    for (int c = 0; c < DEPTH / 4; ++c) {
        f4 p = prow[c];
        prod *= (1.0f - 2.0f * p);
    }
    g_gains[j] = 0.5f * (prod.x * prod.y * prod.z * prod.w);
}

// ---------------------------------------------------------------------------
// Kernel 2: pure stream. Depth scan collapses analytically: s=x0+x1 invariant,
// d=x0-x1 scales by g. out0 = 0.5*s + d*(0.5*g), out1 = 0.5*s - d*(0.5*g).
//
// Nontemporal hints are REQUIRED (Round-6 A/B: temporal regressed 65->86 us;
// WRITE_SIZE unchanged -> IC never absorbs the writes, nt avoids allocate
// churn against the poison-dirty cache).
//
// 4-row batched pipeline: 8 loads issued back-to-back, then 4 compute+store
// pairs, then the next batch. Quadruples outstanding loads per wave vs the
// Round-4 2-deep pipeline and bursts the stores, cutting per-iteration
// vmcnt-FIFO stalls.
// ---------------------------------------------------------------------------
__global__ void __launch_bounds__(NTHREADS)
butterfly_fused(const float* __restrict__ X,
                float* __restrict__ out) {
    const int tid0  = blockIdx.x * NTHREADS + threadIdx.x;
    const int jv    = tid0 & (PAIRS4 - 1);      // float4-pair index, constant
    const int brow0 = tid0 >> 7;                // first row, 0..4095

    const float* xbase = X   + (long long)brow0 * WIDTH + 4 * jv;
    float*       obase = out + (long long)brow0 * WIDTH + 4 * jv;

    // One coalesced, L2-resident 16B load of this thread's 4 gains.
    const f4 g2 = ((const f4*)g_gains)[jv];

#pragma unroll
    for (int t = 0; t < ROWS_PER_THREAD / BATCH_ROWS; ++t) {
        f4 a[BATCH_ROWS], b[BATCH_ROWS];

        // Issue all 8 loads back-to-back (maximum MLP within the batch).
#pragma unroll
        for (int k = 0; k < BATCH_ROWS; ++k) {
            const long long off =
                (long long)(t * BATCH_ROWS + k) * ROW_STRIDE * WIDTH;
            a[k] = __builtin_nontemporal_load((const f4*)(xbase + off));
            b[k] = __builtin_nontemporal_load((const f4*)(xbase + off + HALF));
        }

        // Compute + store burst.
#pragma unroll
        for (int k = 0; k < BATCH_ROWS; ++k) {
            const long long off =
                (long long)(t * BATCH_ROWS + k) * ROW_STRIDE * WIDTH;
            f4 h = 0.5f * a[k] + 0.5f * b[k];
            f4 e = (a[k] - b[k]) * g2;
            __builtin_nontemporal_store(h + e, (f4*)(obase + off));
            __builtin_nontemporal_store(h - e, (f4*)(obase + off + HALF));
        }
    }
}

extern "C" void kernel_launch(void* const* d_in, const int* in_sizes, int n_in,
                              void* d_out, int out_size, void* d_ws, size_t ws_size,
                              hipStream_t stream) {
    const float* X      = (const float*)d_in[0];
    const float* params = (const float*)d_in[1];
    float* out = (float*)d_out;

    hipLaunchKernelGGL(compute_gains, dim3(2), dim3(256), 0, stream, params);
    hipLaunchKernelGGL(butterfly_fused, dim3(NBLOCKS), dim3(NTHREADS), 0, stream,
                       X, out);
}